// Round 1
// baseline (1838.883 us; speedup 1.0000x reference)
//
#include <hip/hip_runtime.h>

// LightGCN: final = (x0 + x1 + x2 + x3) / 4 where x_{l+1}[row] += x_l[col]*norm
// norm[e] = rsqrt(deg[row[e]]) * rsqrt(deg[col[e]]), deg = clip(bincount(row),1)
// N = 150000 nodes, d = 64, E = 2.4M edges, fp32 throughout.

#define NUM_USERS 100000
#define NUM_ITEMS 50000
#define EMBED_DIM 64
#define N_NODES   150000
#define N_EDGES   2400000

// ws layout (bytes):
//   deg  : [0,            600000)    int32 x 150000
//   norm : [600064,       10200064)  f32 x 2.4M
//   xA   : [10200064,     48600064)  f32 x 9.6M
//   xB   : [48600064,     87000064)  f32 x 9.6M
#define OFF_NORM 600064
#define OFF_XA   10200064
#define OFF_XB   48600064

__global__ void bincount_kernel(const int* __restrict__ row, int* __restrict__ deg) {
    int i = blockIdx.x * blockDim.x + threadIdx.x;
    if (i < N_EDGES) atomicAdd(&deg[row[i]], 1);
}

__global__ void norm_kernel(const int* __restrict__ row, const int* __restrict__ col,
                            const int* __restrict__ deg, float* __restrict__ norm) {
    int i = blockIdx.x * blockDim.x + threadIdx.x;
    if (i < N_EDGES) {
        int dr = deg[row[i]]; if (dr < 1) dr = 1;
        int dc = deg[col[i]]; if (dc < 1) dc = 1;
        norm[i] = (1.0f / sqrtf((float)dr)) * (1.0f / sqrtf((float)dc));
    }
}

// concat(user, item) -> xA, and initialize acc (d_out) with the same values.
// 9.6M floats = 2.4M float4; user part = 1.6M float4.
__global__ void init_kernel(const float4* __restrict__ user, const float4* __restrict__ item,
                            float4* __restrict__ xA, float4* __restrict__ acc) {
    int i = blockIdx.x * blockDim.x + threadIdx.x;
    if (i < 2400000) {
        float4 v = (i < 1600000) ? user[i] : item[i - 1600000];
        xA[i]  = v;
        acc[i] = v;
    }
}

// One 64-lane wave per edge; lane = embedding dim. 4 edges per 256-thread block.
__global__ void scatter_kernel(const int* __restrict__ row, const int* __restrict__ col,
                               const float* __restrict__ norm,
                               const float* __restrict__ xin, float* __restrict__ xout) {
    int e = blockIdx.x * 4 + (threadIdx.x >> 6);
    if (e >= N_EDGES) return;
    int lane = threadIdx.x & 63;
    int r = row[e];
    int c = col[e];
    float nv = norm[e];
    float v = xin[(size_t)c * EMBED_DIM + lane] * nv;
    atomicAdd(&xout[(size_t)r * EMBED_DIM + lane], v);
}

__global__ void acc_add_kernel(float4* __restrict__ acc, const float4* __restrict__ x) {
    int i = blockIdx.x * blockDim.x + threadIdx.x;
    if (i < 2400000) {
        float4 a = acc[i]; float4 b = x[i];
        a.x += b.x; a.y += b.y; a.z += b.z; a.w += b.w;
        acc[i] = a;
    }
}

__global__ void acc_add_scale_kernel(float4* __restrict__ acc, const float4* __restrict__ x) {
    int i = blockIdx.x * blockDim.x + threadIdx.x;
    if (i < 2400000) {
        float4 a = acc[i]; float4 b = x[i];
        a.x = (a.x + b.x) * 0.25f; a.y = (a.y + b.y) * 0.25f;
        a.z = (a.z + b.z) * 0.25f; a.w = (a.w + b.w) * 0.25f;
        acc[i] = a;
    }
}

extern "C" void kernel_launch(void* const* d_in, const int* in_sizes, int n_in,
                              void* d_out, int out_size, void* d_ws, size_t ws_size,
                              hipStream_t stream) {
    const float* user = (const float*)d_in[0];
    const float* item = (const float*)d_in[1];
    const int*   ei   = (const int*)d_in[2];
    const int* row = ei;            // edge_index[0]
    const int* col = ei + N_EDGES;  // edge_index[1]

    char*  ws   = (char*)d_ws;
    int*   deg  = (int*)ws;
    float* norm = (float*)(ws + OFF_NORM);
    float* xA   = (float*)(ws + OFF_XA);
    float* xB   = (float*)(ws + OFF_XB);
    float* acc  = (float*)d_out;

    // degree + norm (layer-invariant)
    hipMemsetAsync(deg, 0, N_NODES * sizeof(int), stream);
    bincount_kernel<<<(N_EDGES + 255) / 256, 256, 0, stream>>>(row, deg);
    norm_kernel<<<(N_EDGES + 255) / 256, 256, 0, stream>>>(row, col, deg, norm);

    // x0 = concat(user, item); acc = x0
    init_kernel<<<(2400000 + 255) / 256, 256, 0, stream>>>(
        (const float4*)user, (const float4*)item, (float4*)xA, (float4*)acc);

    float* xin = xA;
    float* xout = xB;
    for (int l = 0; l < 3; ++l) {
        hipMemsetAsync(xout, 0, (size_t)N_NODES * EMBED_DIM * sizeof(float), stream);
        scatter_kernel<<<(N_EDGES + 3) / 4, 256, 0, stream>>>(row, col, norm, xin, xout);
        if (l < 2)
            acc_add_kernel<<<(2400000 + 255) / 256, 256, 0, stream>>>((float4*)acc, (const float4*)xout);
        else
            acc_add_scale_kernel<<<(2400000 + 255) / 256, 256, 0, stream>>>((float4*)acc, (const float4*)xout);
        float* t = xin; xin = xout; xout = t;
    }
}

// Round 2
// 1142.604 us; speedup vs baseline: 1.6094x; 1.6094x over previous
//
#include <hip/hip_runtime.h>

// LightGCN: final = (x0 + x1 + x2 + x3) / 4, x_{l+1}[r] = sum_{e:row=r} x_l[col_e]*norm_e
// norm_e = rsqrt(deg[row_e]) * rsqrt(deg[col_e]), deg = clip(bincount(row),1)
// N = 150000 nodes, d = 64, E = 2.4M edges, fp32.
//
// R2 strategy: counting-sort edges by row -> CSR, then node-parallel PULL
// (one wave per node, no atomics on the embedding, acc fused into epilogue).

#define NUM_USERS 100000
#define NUM_ITEMS 50000
#define EMBED_DIM 64
#define N_NODES   150000
#define N_EDGES   2400000

// ws layout (byte offsets, 64-aligned):
//   rowptr : int32 x (N+1)   [0,          600064)
//   cursor : int32 x N       [600064,     1200128)   (also temp deg counts)
//   rsqd   : f32   x N       [1200128,    1800192)
//   scol   : int32 x E       [1800192,    11400256)
//   xA     : f32   x N*64    [11400256,   49800320)
//   xB     : f32   x N*64    [49800320,   88200384)
#define OFF_ROWPTR 0
#define OFF_CURSOR 600064
#define OFF_RSQD   1200128
#define OFF_SCOL   1800192
#define OFF_XA     11400256
#define OFF_XB     49800320

__global__ void bincount_kernel(const int* __restrict__ row, int* __restrict__ cnt) {
    int i = blockIdx.x * blockDim.x + threadIdx.x;
    if (i < N_EDGES) atomicAdd(&cnt[row[i]], 1);
}

// Single-workgroup sequential-chunk scan: rowptr = exclusive_scan(cnt), rowptr[N]=E,
// cursor = rowptr (write cursors for bucket sort), rsqd = rsqrt(max(cnt,1)).
__global__ void scan_kernel(const int* __restrict__ cnt, int* __restrict__ rowptr,
                            int* __restrict__ cursor, float* __restrict__ rsqd) {
    __shared__ int lds[1024];
    __shared__ int carry_s;
    if (threadIdx.x == 0) carry_s = 0;
    __syncthreads();
    for (int base = 0; base < N_NODES; base += 1024) {
        int i = base + (int)threadIdx.x;
        int v = (i < N_NODES) ? cnt[i] : 0;
        lds[threadIdx.x] = v;
        __syncthreads();
        for (int off = 1; off < 1024; off <<= 1) {
            int t = (threadIdx.x >= off) ? lds[threadIdx.x - off] : 0;
            __syncthreads();
            lds[threadIdx.x] += t;
            __syncthreads();
        }
        int incl = lds[threadIdx.x];
        int carry = carry_s;
        int excl = incl - v + carry;
        if (i < N_NODES) {
            rowptr[i] = excl;
            cursor[i] = excl;
            int d = v < 1 ? 1 : v;
            rsqd[i] = rsqrtf((float)d);
        }
        __syncthreads();
        if (threadIdx.x == 1023) carry_s = carry + incl;
        __syncthreads();
    }
    if (threadIdx.x == 0) rowptr[N_NODES] = carry_s;
}

// Bucket-scatter cols into row-sorted order. Within-row order nondeterministic (fp
// sum order differs from ref; error well under threshold — verified pattern R1).
__global__ void sort_kernel(const int* __restrict__ row, const int* __restrict__ col,
                            int* __restrict__ cursor, int* __restrict__ scol) {
    int e = blockIdx.x * blockDim.x + threadIdx.x;
    if (e < N_EDGES) {
        int r = row[e];
        int pos = atomicAdd(&cursor[r], 1);
        scol[pos] = col[e];
    }
}

// concat(user, item) -> xA and acc. 9.6M floats = 2.4M float4.
__global__ void init_kernel(const float4* __restrict__ user, const float4* __restrict__ item,
                            float4* __restrict__ xA, float4* __restrict__ acc) {
    int i = blockIdx.x * blockDim.x + threadIdx.x;
    if (i < 2400000) {
        float4 v = (i < 1600000) ? user[i] : item[i - 1600000];
        xA[i]  = v;
        acc[i] = v;
    }
}

// One wave per node, lane = embed dim. 4 nodes per 256-thread block.
template <bool LAST>
__global__ void pull_kernel(const int* __restrict__ rowptr, const int* __restrict__ scol,
                            const float* __restrict__ rsqd,
                            const float* __restrict__ xin, float* __restrict__ xout,
                            float* __restrict__ acc) {
    int n = blockIdx.x * 4 + ((int)threadIdx.x >> 6);
    if (n >= N_NODES) return;
    int lane = threadIdx.x & 63;
    int j   = rowptr[n];
    int end = rowptr[n + 1];
    float rn = rsqd[n];
    float sum = 0.0f;
    // 2-wide unroll for memory-level parallelism on the gathers
    for (; j + 1 < end; j += 2) {
        int c0 = scol[j], c1 = scol[j + 1];
        float nv0 = rn * rsqd[c0];
        float nv1 = rn * rsqd[c1];
        float v0 = xin[(size_t)c0 * EMBED_DIM + lane];
        float v1 = xin[(size_t)c1 * EMBED_DIM + lane];
        sum += v0 * nv0 + v1 * nv1;
    }
    if (j < end) {
        int c0 = scol[j];
        sum += xin[(size_t)c0 * EMBED_DIM + lane] * (rn * rsqd[c0]);
    }
    size_t o = (size_t)n * EMBED_DIM + lane;
    if (!LAST) {
        xout[o] = sum;
        acc[o] += sum;
    } else {
        acc[o] = (acc[o] + sum) * 0.25f;
    }
}

extern "C" void kernel_launch(void* const* d_in, const int* in_sizes, int n_in,
                              void* d_out, int out_size, void* d_ws, size_t ws_size,
                              hipStream_t stream) {
    const float* user = (const float*)d_in[0];
    const float* item = (const float*)d_in[1];
    const int*   ei   = (const int*)d_in[2];
    const int* row = ei;            // edge_index[0]
    const int* col = ei + N_EDGES;  // edge_index[1]

    char*  ws     = (char*)d_ws;
    int*   rowptr = (int*)(ws + OFF_ROWPTR);
    int*   cursor = (int*)(ws + OFF_CURSOR);   // also temp deg counts
    float* rsqd   = (float*)(ws + OFF_RSQD);
    int*   scol   = (int*)(ws + OFF_SCOL);
    float* xA     = (float*)(ws + OFF_XA);
    float* xB     = (float*)(ws + OFF_XB);
    float* acc    = (float*)d_out;

    // CSR build (layer-invariant)
    hipMemsetAsync(cursor, 0, N_NODES * sizeof(int), stream);
    bincount_kernel<<<(N_EDGES + 255) / 256, 256, 0, stream>>>(row, cursor);
    scan_kernel<<<1, 1024, 0, stream>>>(cursor, rowptr, cursor, rsqd);
    // NOTE: scan reads cnt (=cursor) and rewrites cursor in the same pass;
    // each element is read before being overwritten by the same thread/iter.
    sort_kernel<<<(N_EDGES + 255) / 256, 256, 0, stream>>>(row, col, cursor, scol);

    // x0 = concat(user,item); acc = x0
    init_kernel<<<(2400000 + 255) / 256, 256, 0, stream>>>(
        (const float4*)user, (const float4*)item, (float4*)xA, (float4*)acc);

    // 3 pull layers, acc fused
    const int grid = (N_NODES + 3) / 4;
    pull_kernel<false><<<grid, 256, 0, stream>>>(rowptr, scol, rsqd, xA, xB, acc);
    pull_kernel<false><<<grid, 256, 0, stream>>>(rowptr, scol, rsqd, xB, xA, acc);
    pull_kernel<true ><<<grid, 256, 0, stream>>>(rowptr, scol, rsqd, xA, xB, acc);
}

// Round 3
// 858.397 us; speedup vs baseline: 2.1422x; 1.3311x over previous
//
#include <hip/hip_runtime.h>

// LightGCN: final = (x0 + x1 + x2 + x3) / 4, x_{l+1}[r] = sum_{e:row=r} x_l[col_e]*norm_e
// norm_e = rsqrt(deg[row_e]) * rsqrt(deg[col_e]), deg = clip(bincount(row),1)
// N = 150000 nodes, d = 64, E = 2.4M edges, fp32.
//
// R3: R2's single-workgroup scan was 289 us (0.19% occupancy). Replaced with a
// two-level parallel scan (local-scan / blocksum-scan / finalize), ~10 us total.

#define NUM_USERS 100000
#define NUM_ITEMS 50000
#define EMBED_DIM 64
#define N_NODES   150000
#define N_EDGES   2400000
#define SCAN_BLOCKS 147   // ceil(150000/1024)

// ws layout (byte offsets):
//   rowptr   : int32 x (N+1) [0,          600064)
//   cursor   : int32 x N     [600064,     1200128)   (also temp deg counts)
//   rsqd     : f32   x N     [1200128,    1800192)
//   blocksum : int32 x 160   [1800192,    1800832)
//   scol     : int32 x E     [1800832,    11400896)
//   xA       : f32   x N*64  [11400896,   49800960)
//   xB       : f32   x N*64  [49800960,   88201024)
#define OFF_ROWPTR   0
#define OFF_CURSOR   600064
#define OFF_RSQD     1200128
#define OFF_BLOCKSUM 1800192
#define OFF_SCOL     1800832
#define OFF_XA       11400896
#define OFF_XB       49800960

__global__ void bincount_kernel(const int* __restrict__ row, int* __restrict__ cnt) {
    int i = blockIdx.x * blockDim.x + threadIdx.x;
    if (i < N_EDGES) atomicAdd(&cnt[row[i]], 1);
}

// Stage A: per-block local exclusive scan of cnt -> rowptr (local), block total -> blocksum.
__global__ void scan_local_kernel(const int* __restrict__ cnt, int* __restrict__ rowptr,
                                  int* __restrict__ blocksum) {
    __shared__ int lds[1024];
    int i = blockIdx.x * 1024 + (int)threadIdx.x;
    int v = (i < N_NODES) ? cnt[i] : 0;
    lds[threadIdx.x] = v;
    __syncthreads();
    for (int off = 1; off < 1024; off <<= 1) {
        int t = (threadIdx.x >= off) ? lds[threadIdx.x - off] : 0;
        __syncthreads();
        lds[threadIdx.x] += t;
        __syncthreads();
    }
    int incl = lds[threadIdx.x];
    if (i < N_NODES) rowptr[i] = incl - v;   // local exclusive
    if (threadIdx.x == 1023) blocksum[blockIdx.x] = incl;
}

// Stage B: exclusive scan of the 147 block sums, in place. One block.
__global__ void scan_blocksum_kernel(int* __restrict__ blocksum) {
    __shared__ int lds[256];
    int t = threadIdx.x;
    int v = (t < SCAN_BLOCKS) ? blocksum[t] : 0;
    lds[t] = v;
    __syncthreads();
    for (int off = 1; off < 256; off <<= 1) {
        int x = (t >= off) ? lds[t - off] : 0;
        __syncthreads();
        lds[t] += x;
        __syncthreads();
    }
    if (t < SCAN_BLOCKS) blocksum[t] = lds[t] - v;  // exclusive
}

// Stage C: add block offsets; emit final rowptr, cursor copy, rsqd = rsqrt(max(cnt,1)).
__global__ void scan_finalize_kernel(const int* __restrict__ cnt, const int* __restrict__ blocksum,
                                     int* __restrict__ rowptr, int* __restrict__ cursor,
                                     float* __restrict__ rsqd) {
    int i = blockIdx.x * 1024 + (int)threadIdx.x;
    if (i < N_NODES) {
        int excl = rowptr[i] + blocksum[blockIdx.x];
        rowptr[i] = excl;
        cursor[i] = excl;
        int v = cnt[i];
        int d = v < 1 ? 1 : v;
        rsqd[i] = rsqrtf((float)d);
    }
    if (i == 0) rowptr[N_NODES] = N_EDGES;
}

// Bucket-scatter cols into row-sorted order (within-row order nondeterministic; fp error OK).
__global__ void sort_kernel(const int* __restrict__ row, const int* __restrict__ col,
                            int* __restrict__ cursor, int* __restrict__ scol) {
    int e = blockIdx.x * blockDim.x + threadIdx.x;
    if (e < N_EDGES) {
        int r = row[e];
        int pos = atomicAdd(&cursor[r], 1);
        scol[pos] = col[e];
    }
}

// concat(user, item) -> xA and acc. 9.6M floats = 2.4M float4.
__global__ void init_kernel(const float4* __restrict__ user, const float4* __restrict__ item,
                            float4* __restrict__ xA, float4* __restrict__ acc) {
    int i = blockIdx.x * blockDim.x + threadIdx.x;
    if (i < 2400000) {
        float4 v = (i < 1600000) ? user[i] : item[i - 1600000];
        xA[i]  = v;
        acc[i] = v;
    }
}

// One wave per node, lane = embed dim. 4 nodes per 256-thread block.
template <bool LAST>
__global__ void pull_kernel(const int* __restrict__ rowptr, const int* __restrict__ scol,
                            const float* __restrict__ rsqd,
                            const float* __restrict__ xin, float* __restrict__ xout,
                            float* __restrict__ acc) {
    int n = blockIdx.x * 4 + ((int)threadIdx.x >> 6);
    if (n >= N_NODES) return;
    int lane = threadIdx.x & 63;
    int j   = rowptr[n];
    int end = rowptr[n + 1];
    float rn = rsqd[n];
    float sum = 0.0f;
    for (; j + 1 < end; j += 2) {
        int c0 = scol[j], c1 = scol[j + 1];
        float nv0 = rn * rsqd[c0];
        float nv1 = rn * rsqd[c1];
        float v0 = xin[(size_t)c0 * EMBED_DIM + lane];
        float v1 = xin[(size_t)c1 * EMBED_DIM + lane];
        sum += v0 * nv0 + v1 * nv1;
    }
    if (j < end) {
        int c0 = scol[j];
        sum += xin[(size_t)c0 * EMBED_DIM + lane] * (rn * rsqd[c0]);
    }
    size_t o = (size_t)n * EMBED_DIM + lane;
    if (!LAST) {
        xout[o] = sum;
        acc[o] += sum;
    } else {
        acc[o] = (acc[o] + sum) * 0.25f;
    }
}

extern "C" void kernel_launch(void* const* d_in, const int* in_sizes, int n_in,
                              void* d_out, int out_size, void* d_ws, size_t ws_size,
                              hipStream_t stream) {
    const float* user = (const float*)d_in[0];
    const float* item = (const float*)d_in[1];
    const int*   ei   = (const int*)d_in[2];
    const int* row = ei;            // edge_index[0]
    const int* col = ei + N_EDGES;  // edge_index[1]

    char*  ws       = (char*)d_ws;
    int*   rowptr   = (int*)(ws + OFF_ROWPTR);
    int*   cursor   = (int*)(ws + OFF_CURSOR);   // also temp deg counts
    float* rsqd     = (float*)(ws + OFF_RSQD);
    int*   blocksum = (int*)(ws + OFF_BLOCKSUM);
    int*   scol     = (int*)(ws + OFF_SCOL);
    float* xA       = (float*)(ws + OFF_XA);
    float* xB       = (float*)(ws + OFF_XB);
    float* acc      = (float*)d_out;

    // CSR build (layer-invariant)
    hipMemsetAsync(cursor, 0, N_NODES * sizeof(int), stream);
    bincount_kernel<<<(N_EDGES + 255) / 256, 256, 0, stream>>>(row, cursor);
    scan_local_kernel<<<SCAN_BLOCKS, 1024, 0, stream>>>(cursor, rowptr, blocksum);
    scan_blocksum_kernel<<<1, 256, 0, stream>>>(blocksum);
    scan_finalize_kernel<<<SCAN_BLOCKS, 1024, 0, stream>>>(cursor, blocksum, rowptr, cursor, rsqd);
    sort_kernel<<<(N_EDGES + 255) / 256, 256, 0, stream>>>(row, col, cursor, scol);

    // x0 = concat(user,item); acc = x0
    init_kernel<<<(2400000 + 255) / 256, 256, 0, stream>>>(
        (const float4*)user, (const float4*)item, (float4*)xA, (float4*)acc);

    // 3 pull layers, acc fused
    const int grid = (N_NODES + 3) / 4;
    pull_kernel<false><<<grid, 256, 0, stream>>>(rowptr, scol, rsqd, xA, xB, acc);
    pull_kernel<false><<<grid, 256, 0, stream>>>(rowptr, scol, rsqd, xB, xA, acc);
    pull_kernel<true ><<<grid, 256, 0, stream>>>(rowptr, scol, rsqd, xA, xB, acc);
}